// Round 9
// baseline (197.137 us; speedup 1.0000x reference)
//
#include <hip/hip_runtime.h>
#include <math.h>

// GAT layer, R28: MEASUREMENT ROUND. R27 (passing, 181us) with the fused
// k_gemm split into two dispatches for attribution:
//   k_mm:   the 625 MFMA GEMM tile blocks ONLY (also drops the 5KB LDS the
//           fused kernel forced on them).
//   k_scat: the 84 hist+claim+scatter blocks, byte-identical logic.
// Six structurally different edge passes (R19,R21-R24,R27) all pinned the
// fused kernel at 45+-5us; occupancy arithmetic (12.6% observed) favors
// edge-blocks-straggle, but fused dispatch gives no attribution. This round
// buys the number at the cost of losing GEMM||scatter overlap (+1 launch).
// Committed prediction: edge-straggler -> k_scat 38-44 (top-5 visible),
// k_mm 5-10 (invisible), total 184-190. GEMM-straggler -> k_mm 40-45.
// Pipeline: init -> mm -> scat -> bfin -> gather -> bnstats -> final.

constexpr float NEG_SLOPE = 0.2f;
constexpr float BN_EPS = 1e-5f;
constexpr float SM_EPS = 1e-16f;
constexpr int NBUCK = 640;   // coarse buckets (dst>>6), covers n <= 40960
constexpr int IPB   = 8192;  // items per scatter block
constexpr int BCAP  = 1536;  // bucket capacity (mean 1088, +13.6 sigma)

typedef __attribute__((ext_vector_type(8))) short short8;   // 8 bf16
typedef __attribute__((ext_vector_type(4))) float f32x4;    // MFMA acc

__device__ inline unsigned bf16rne(float f) {
    unsigned b = __float_as_uint(f);
    return (b + 0x7fffu + ((b >> 16) & 1u)) >> 16;
}

// ---------------------------------------------------------------------------
// K0: b<64: Wt transpose. b<72: WS/WD fused attention columns. b>=72: zero
// stats(256) | bcur(640) | deg(n).  (== R27)
// ---------------------------------------------------------------------------
__global__ __launch_bounds__(256) void k_init(
    const float* __restrict__ W, const float* __restrict__ att_src,
    const float* __restrict__ att_dst, unsigned short* __restrict__ Wtg,
    int* __restrict__ zbase, int zcount)
{
    int b = blockIdx.x;
    if (b < 64) {
        int idx = b * 256 + threadIdx.x;   // 16384 total
        int k = idx >> 7, nc = idx & 127;
        Wtg[nc * 128 + k] = (unsigned short)bf16rne(W[idx]);
    } else if (b < 72) {
        int c = (b - 64) * 16 + (threadIdx.x >> 4);
        int j = threadIdx.x & 15;
        int h = j & 7;
        const float* att = (j < 8) ? att_src : att_dst;
        float v = 0.f;
#pragma unroll
        for (int f = 0; f < 16; ++f)
            v += W[c * 128 + h * 16 + f] * att[h * 16 + f];
        Wtg[(128 + j) * 128 + c] = (unsigned short)bf16rne(v);
    } else {
        int idx = (b - 72) * 256 + threadIdx.x;
        if (idx < zcount) zbase[idx] = 0;
    }
}

// ---------------------------------------------------------------------------
// K1: GEMM tiles only (== R27's GEMM branch, no LDS).
// ---------------------------------------------------------------------------
__global__ __launch_bounds__(256) void k_mm(
    const float* __restrict__ x, const unsigned short* __restrict__ Wtg,
    unsigned* __restrict__ xpb, float* __restrict__ a_s, float* __restrict__ a_d,
    int n)
{
    const int tid = threadIdx.x;
    const int lane = tid & 63;
    const int wid = tid >> 6;
    const int quad = lane >> 4;
    const int l16 = lane & 15;
    const int row = blockIdx.x * 64 + wid * 16 + l16;

    const float4* x4 = (const float4*)x;
    short8 afrag[4];
#pragma unroll
    for (int kt = 0; kt < 4; ++kt) {
        float4 f0 = make_float4(0.f, 0.f, 0.f, 0.f), f1 = f0;
        if (row < n) {
            f0 = x4[(size_t)row * 32 + kt * 8 + quad * 2];
            f1 = x4[(size_t)row * 32 + kt * 8 + quad * 2 + 1];
        }
        short8 a;
        a[0] = (short)bf16rne(f0.x); a[1] = (short)bf16rne(f0.y);
        a[2] = (short)bf16rne(f0.z); a[3] = (short)bf16rne(f0.w);
        a[4] = (short)bf16rne(f1.x); a[5] = (short)bf16rne(f1.y);
        a[6] = (short)bf16rne(f1.z); a[7] = (short)bf16rne(f1.w);
        afrag[kt] = a;
    }

    f32x4 acc[9];
#pragma unroll
    for (int ct = 0; ct < 9; ++ct) acc[ct] = (f32x4){0.f, 0.f, 0.f, 0.f};

#pragma unroll
    for (int ct = 0; ct < 9; ++ct) {
#pragma unroll
        for (int kt = 0; kt < 4; ++kt) {
            short8 bfr = *(const short8*)&Wtg[(size_t)(ct * 16 + l16) * 128 + kt * 32 + quad * 8];
            acc[ct] = __builtin_amdgcn_mfma_f32_16x16x32_bf16(afrag[kt], bfr, acc[ct], 0, 0, 0);
        }
    }

    const int rowbase = blockIdx.x * 64 + wid * 16 + quad * 4;
#pragma unroll
    for (int ct = 0; ct < 8; ++ct) {
#pragma unroll
        for (int r = 0; r < 4; ++r) {
            float val = acc[ct][r];
            float other = __shfl_xor(val, 1);
            int orow = rowbase + r;
            if (!(lane & 1) && orow < n) {
                unsigned u = bf16rne(val) | (bf16rne(other) << 16);
                xpb[(size_t)orow * 64 + ct * 8 + (l16 >> 1)] = u;
            }
        }
    }
#pragma unroll
    for (int r = 0; r < 4; ++r) {
        int orow = rowbase + r;
        if (orow < n) {
            float val = acc[8][r];
            if (l16 < 8) a_s[(size_t)orow * 8 + l16] = val;
            else         a_d[(size_t)orow * 8 + (l16 - 8)] = val;
        }
    }
}

// ---------------------------------------------------------------------------
// K2: chunk scatter (== R27's edge branch): LDS hist -> 1 global atomicAdd
// per non-empty bucket -> LDS-cursor scatter into fixed bucket segments.
// ---------------------------------------------------------------------------
__global__ __launch_bounds__(256) void k_scat(
    const int* __restrict__ ei, int E,
    int* __restrict__ bcur, unsigned* __restrict__ buck, int n)
{
    __shared__ int lh[NBUCK];
    __shared__ int cur[NBUCK];
    const int blkC = blockIdx.x;
    const int T = E + n;
    for (int i = threadIdx.x; i < NBUCK; i += 256) lh[i] = 0;
    __syncthreads();
    const int base = blkC * IPB;
#pragma unroll
    for (int i = 0; i < IPB / 256; ++i) {
        int t = base + i * 256 + threadIdx.x;
        if (t < T) {
            int dst = (t < E) ? ei[E + t] : (t - E);
            atomicAdd(&lh[dst >> 6], 1);
        }
    }
    __syncthreads();
    for (int i = threadIdx.x; i < NBUCK; i += 256) {
        int c = lh[i];
        cur[i] = (c > 0) ? atomicAdd(&bcur[i], c) : 0;   // block's base
    }
    __syncthreads();
#pragma unroll
    for (int i = 0; i < IPB / 256; ++i) {
        int t = base + i * 256 + threadIdx.x;
        if (t < T) {
            int dst, src;
            if (t < E) { dst = ei[E + t]; src = ei[t]; }
            else       { dst = src = t - E; }
            int bk = dst >> 6;
            int local = atomicAdd(&cur[bk], 1);          // LDS cursor
            if (local < BCAP)
                buck[(size_t)bk * BCAP + local] =
                    ((unsigned)dst << 16) | (unsigned)src;
        }
    }
}

// ---------------------------------------------------------------------------
// K3: per-bucket finish (== R27). LDS counting sort by dst&63 ->
// deg/rowst + coalesced writeback.
// ---------------------------------------------------------------------------
__global__ __launch_bounds__(256) void k_bfin(
    const int* __restrict__ bcur, unsigned* __restrict__ buck,
    int* __restrict__ deg, int* __restrict__ rowst, int n)
{
    const int k = blockIdx.x;
    const int start = k * BCAP;
    const int cnt = min(bcur[k], BCAP);
    __shared__ unsigned it[BCAP];
    __shared__ unsigned so[BCAP];
    __shared__ int h[64], pf[64], curs[64];
    for (int i = threadIdx.x; i < cnt; i += 256) it[i] = buck[start + i];
    if (threadIdx.x < 64) h[threadIdx.x] = 0;
    __syncthreads();
    for (int i = threadIdx.x; i < cnt; i += 256)
        atomicAdd(&h[(it[i] >> 16) & 63], 1);
    __syncthreads();
    if (threadIdx.x < 64) {
        int p = 0;
        for (int j = 0; j < threadIdx.x; ++j) p += h[j];
        pf[threadIdx.x] = p;
        curs[threadIdx.x] = p;
    }
    __syncthreads();
    for (int i = threadIdx.x; i < cnt; i += 256) {
        unsigned v = it[i];
        int r = atomicAdd(&curs[(v >> 16) & 63], 1);
        so[r] = v;
    }
    __syncthreads();
    for (int i = threadIdx.x; i < cnt; i += 256) buck[start + i] = so[i];
    if (threadIdx.x < 64) {
        int dst = (k << 6) + threadIdx.x;
        if (dst < n) {
            deg[dst] = h[threadIdx.x];
            rowst[dst] = start + pf[threadIdx.x];
        }
    }
}

// ---------------------------------------------------------------------------
// K4: per-dst gather-aggregate from the sorted bucket array. (== R27)
// ---------------------------------------------------------------------------
__global__ __launch_bounds__(256) void k_gather(
    const int* __restrict__ deg, const int* __restrict__ rowst,
    const unsigned* __restrict__ buck,
    const float* __restrict__ a_s, const float* __restrict__ a_d,
    const unsigned* __restrict__ xpb, unsigned* __restrict__ aggb, int n)
{
    int node = blockIdx.x * 4 + (threadIdx.x >> 6);
    if (node >= n) return;
    int lane = threadIdx.x & 63;
    int h = lane >> 3;
    float ad = a_d[(size_t)node * 8 + h];
    const unsigned* rowp = buck + rowst[node];
    int cnt = deg[node];
    float acc0 = 0.f, acc1 = 0.f, s = 0.f;

    for (int slot = 0; slot < cnt; slot += 8) {
        int sx[8]; float w[8]; unsigned u[8];
#pragma unroll
        for (int j = 0; j < 8; ++j) {
            int sj = slot + j;
            sx[j] = (int)(rowp[sj < cnt ? sj : cnt - 1] & 0xffffu);
        }
#pragma unroll
        for (int j = 0; j < 8; ++j) w[j] = a_s[(size_t)sx[j] * 8 + h];
#pragma unroll
        for (int j = 0; j < 8; ++j) u[j] = xpb[(size_t)sx[j] * 64 + lane];
#pragma unroll
        for (int j = 0; j < 8; ++j) {
            float v = w[j] + ad;
            v = v > 0.f ? v : NEG_SLOPE * v;
            float p = __expf(v);
            p = (slot + j < cnt) ? p : 0.f;
            s += p;
            acc0 = fmaf(p, __uint_as_float(u[j] << 16), acc0);
            acc1 = fmaf(p, __uint_as_float(u[j] & 0xffff0000u), acc1);
        }
    }
    float inv = 1.0f / (s + SM_EPS);
    aggb[(size_t)node * 64 + lane] = bf16rne(acc0 * inv) | (bf16rne(acc1 * inv) << 16);
}

// ---------------------------------------------------------------------------
// K5: per-channel sum / sumsq of agg (bf16). (== R27)
// ---------------------------------------------------------------------------
__global__ __launch_bounds__(256) void k_bnstats(
    const unsigned* __restrict__ aggb, int n, float* __restrict__ stats)
{
    __shared__ float red[4][256];   // [rowgroup][0:128 sums | 128:256 sumsq]
    const int cp = threadIdx.x & 63;       // channel pair: c = 2cp, 2cp+1
    const int rg = threadIdx.x >> 6;       // row group 0..3
    float s0 = 0.f, s1 = 0.f, q0 = 0.f, q1 = 0.f;
    for (int r = blockIdx.x * 4 + rg; r < n; r += gridDim.x * 4) {
        unsigned u = aggb[(size_t)r * 64 + cp];
        float v0 = __uint_as_float(u << 16);
        float v1 = __uint_as_float(u & 0xffff0000u);
        s0 += v0; q0 += v0 * v0;
        s1 += v1; q1 += v1 * v1;
    }
    red[rg][cp * 2] = s0;       red[rg][cp * 2 + 1] = s1;
    red[rg][128 + cp * 2] = q0; red[rg][128 + cp * 2 + 1] = q1;
    __syncthreads();
    int idx = threadIdx.x;
    float v = red[0][idx] + red[1][idx] + red[2][idx] + red[3][idx];
    if (idx < 128) atomicAdd(&stats[idx], v);
    else           atomicAdd(&stats[128 + (idx - 128)], v);
}

// ---------------------------------------------------------------------------
// K6: finalize: BN (batch stats of agg) + ReLU + residual. (== R27)
// ---------------------------------------------------------------------------
__global__ __launch_bounds__(256) void k_final(
    const unsigned* __restrict__ aggb, const float* __restrict__ gamma,
    const float* __restrict__ beta, const float* __restrict__ stats,
    const float* __restrict__ x, float* __restrict__ out, int n)
{
    int i4 = blockIdx.x * 256 + threadIdx.x;     // index in float4 units
    int total4 = n * 32;
    if (i4 >= total4) return;
    int c4 = (i4 & 31) * 4;                      // channel base
    float invn = 1.0f / (float)n;
    uint2 au = ((const uint2*)aggb)[i4];         // 4 bf16
    float av[4] = { __uint_as_float(au.x << 16), __uint_as_float(au.x & 0xffff0000u),
                    __uint_as_float(au.y << 16), __uint_as_float(au.y & 0xffff0000u) };
    float4 xv = ((const float4*)x)[i4];
    float4 o;
#pragma unroll
    for (int j = 0; j < 4; ++j) {
        int c = c4 + j;
        float mean = stats[c] * invn;
        float var = stats[128 + c] * invn - mean * mean;
        float v = (av[j] - mean) * rsqrtf(var + BN_EPS) * gamma[c] + beta[c];
        v = fmaxf(v, 0.f);
        (&o.x)[j] = v + (&xv.x)[j];
    }
    ((float4*)out)[i4] = o;
}

// ---------------------------------------------------------------------------
extern "C" void kernel_launch(void* const* d_in, const int* in_sizes, int n_in,
                              void* d_out, int out_size, void* d_ws, size_t ws_size,
                              hipStream_t stream)
{
    const float* x        = (const float*)d_in[0];
    const int*   ei       = (const int*)d_in[1];
    const float* W        = (const float*)d_in[2];
    const float* att_src  = (const float*)d_in[3];
    const float* att_dst  = (const float*)d_in[4];
    const float* bn_gamma = (const float*)d_in[6];
    const float* bn_beta  = (const float*)d_in[7];
    float* out = (float*)d_out;

    const int n = in_sizes[0] / 128;
    const int E = in_sizes[1] / 2;
    const int T = E + n;
    const int nba = (T + IPB - 1) / IPB;         // 84 scatter blocks

    // workspace layout: stats | bcur | deg contiguous (zeroed in init)
    float*          stats = (float*)d_ws;                         // 256
    int*            bcur  = (int*)(stats + 256);                  // NBUCK
    int*            deg   = bcur + NBUCK;                         // n
    int*            rowst = deg + n;                              // n
    unsigned short* Wtg   = (unsigned short*)(rowst + n);         // 144*128
    unsigned*       xpb   = (unsigned*)(Wtg + 144 * 128);         // n*64 (bf16 x2)
    unsigned*       aggb  = xpb + (size_t)n * 64;                 // n*64 (bf16 x2)
    float*          a_s   = (float*)(aggb + (size_t)n * 64);      // n*8
    float*          a_d   = a_s + (size_t)n * 8;                  // n*8
    unsigned*       buck  = (unsigned*)(a_d + (size_t)n * 8);     // NBUCK*BCAP

    const int zcount = 256 + NBUCK + n;
    const int ginit = 72 + (zcount + 255) / 256;
    const int ntiles = (n + 63) >> 6;

    k_init<<<ginit, 256, 0, stream>>>(W, att_src, att_dst, Wtg,
                                      (int*)stats, zcount);
    k_mm<<<ntiles, 256, 0, stream>>>(x, Wtg, xpb, a_s, a_d, n);
    k_scat<<<nba, 256, 0, stream>>>(ei, E, bcur, buck, n);
    k_bfin<<<NBUCK, 256, 0, stream>>>(bcur, buck, deg, rowst, n);
    k_gather<<<(n + 3) / 4, 256, 0, stream>>>(deg, rowst, buck, a_s, a_d,
                                              xpb, aggb, n);
    k_bnstats<<<640, 256, 0, stream>>>(aggb, n, stats);
    k_final<<<(n * 32 + 255) / 256, 256, 0, stream>>>(aggb, bn_gamma, bn_beta,
                                                      stats, x, out, n);
}

// Round 10
// 179.856 us; speedup vs baseline: 1.0961x; 1.0961x over previous
//
#include <hip/hip_runtime.h>
#include <math.h>

// GAT layer, R29: R27 (fused gemm+scatter, passing 181us) with the scatter
// rebuilt as LDS-FULL-PRESORT -> COALESCED RUN WRITEOUT.
// Evidence chain: R19-R24 (atomic CSR, ~45us) and R27 (atomic-free scatter,
// ~45us) differ in everything EXCEPT granularity: ~680k line-granularity
// scattered global ops per pass (~17G line-ops/s plateau). R28's split
// showed scat ~35-40 standalone. Fix the granularity: stage the whole 8192-
// item chunk bucket-grouped in LDS (32KB), then write out with consecutive
// lanes hitting consecutive staging slots -> destinations form contiguous
// runs (avg 12.8 items) -> wave stores coalesce to ~5 line segments instead
// of 64. Per-item LDS atomics unchanged vs R27 (clean discriminator: if
// k_gemm stays ~45, the wall is the serial item loops, not global scatter).
// Downstream (bfin/gather/bnstats/final) byte-identical to R27.
// Pipeline: init -> gemm(+scatter) -> bfin -> gather -> bnstats -> final.

constexpr float NEG_SLOPE = 0.2f;
constexpr float BN_EPS = 1e-5f;
constexpr float SM_EPS = 1e-16f;
constexpr int NBUCK = 640;   // coarse buckets (dst>>6), covers n <= 40960
constexpr int IPB   = 8192;  // items per scatter block
constexpr int BCAP  = 1536;  // bucket capacity (mean 1088, +13.6 sigma)

typedef __attribute__((ext_vector_type(8))) short short8;   // 8 bf16
typedef __attribute__((ext_vector_type(4))) float f32x4;    // MFMA acc

__device__ inline unsigned bf16rne(float f) {
    unsigned b = __float_as_uint(f);
    return (b + 0x7fffu + ((b >> 16) & 1u)) >> 16;
}

// ---------------------------------------------------------------------------
// K0: b<64: Wt transpose. b<72: WS/WD fused attention columns. b>=72: zero
// stats(256) | bcur(640) | deg(n).  (== R27)
// ---------------------------------------------------------------------------
__global__ __launch_bounds__(256) void k_init(
    const float* __restrict__ W, const float* __restrict__ att_src,
    const float* __restrict__ att_dst, unsigned short* __restrict__ Wtg,
    int* __restrict__ zbase, int zcount)
{
    int b = blockIdx.x;
    if (b < 64) {
        int idx = b * 256 + threadIdx.x;   // 16384 total
        int k = idx >> 7, nc = idx & 127;
        Wtg[nc * 128 + k] = (unsigned short)bf16rne(W[idx]);
    } else if (b < 72) {
        int c = (b - 64) * 16 + (threadIdx.x >> 4);
        int j = threadIdx.x & 15;
        int h = j & 7;
        const float* att = (j < 8) ? att_src : att_dst;
        float v = 0.f;
#pragma unroll
        for (int f = 0; f < 16; ++f)
            v += W[c * 128 + h * 16 + f] * att[h * 16 + f];
        Wtg[(128 + j) * 128 + c] = (unsigned short)bf16rne(v);
    } else {
        int idx = (b - 72) * 256 + threadIdx.x;
        if (idx < zcount) zbase[idx] = 0;
    }
}

// ---------------------------------------------------------------------------
// K1: role-split. blocks < ntiles: MFMA tiles (== R27). blocks >= ntiles:
// LDS-presort scatter:
//   p1: LDS hist cnt[640]
//   p2: block exclusive scan cnt->off (64 thr x 10), cur2=off, tot
//   p3: claim: cnt[k] <- atomicAdd(&bcur[k], cnt[k])   (global base)
//   p4: stage items bucket-grouped into stg[8192] via LDS cursors
//   p5: writeout stg[i] -> buck[bk*BCAP + cnt[bk] + (i - off[bk])]
//       (consecutive lanes -> consecutive slots -> coalesced runs)
// ---------------------------------------------------------------------------
__global__ __launch_bounds__(256) void k_gemm(
    const float* __restrict__ x, const unsigned short* __restrict__ Wtg,
    const int* __restrict__ ei, int E,
    unsigned* __restrict__ xpb, float* __restrict__ a_s, float* __restrict__ a_d,
    int* __restrict__ bcur, unsigned* __restrict__ buck, int n,
    int ntiles)
{
    __shared__ int cnt[NBUCK];      // p1 hist; p3 re-used as global base
    __shared__ int off[NBUCK];      // block-local exclusive offsets
    __shared__ int cur2[NBUCK];     // p4 staging cursors
    __shared__ unsigned stg[IPB];   // bucket-grouped staging (32KB)
    __shared__ int part[64];
    __shared__ int tot;

    if ((int)blockIdx.x >= ntiles) {
        const int tid = threadIdx.x;
        const int blkC = blockIdx.x - ntiles;
        const int T = E + n;
        for (int i = tid; i < NBUCK; i += 256) cnt[i] = 0;
        __syncthreads();
        const int base = blkC * IPB;
#pragma unroll
        for (int i = 0; i < IPB / 256; ++i) {
            int t = base + i * 256 + tid;
            if (t < T) {
                int dst = (t < E) ? ei[E + t] : (t - E);
                atomicAdd(&cnt[dst >> 6], 1);
            }
        }
        __syncthreads();
        // p2: block-level exclusive scan (640 = 64 threads x 10 buckets)
        if (tid < 64) {
            int s = 0;
#pragma unroll
            for (int j = 0; j < 10; ++j) s += cnt[tid * 10 + j];
            part[tid] = s;
        }
        __syncthreads();
        if (tid == 0) {
            int run = 0;
#pragma unroll
            for (int j = 0; j < 64; ++j) { int v = part[j]; part[j] = run; run += v; }
            tot = run;
        }
        __syncthreads();
        if (tid < 64) {
            int run = part[tid];
#pragma unroll
            for (int j = 0; j < 10; ++j) {
                int k = tid * 10 + j;
                off[k] = run; cur2[k] = run; run += cnt[k];
            }
        }
        __syncthreads();
        // p3: claim global space; cnt[k] becomes this block's global base
        for (int i = tid; i < NBUCK; i += 256) {
            int c = cnt[i];
            cnt[i] = (c > 0) ? atomicAdd(&bcur[i], c) : 0;
        }
        __syncthreads();
        // p4: stage bucket-grouped into LDS
#pragma unroll
        for (int i = 0; i < IPB / 256; ++i) {
            int t = base + i * 256 + tid;
            if (t < T) {
                int dst, src;
                if (t < E) { dst = ei[E + t]; src = ei[t]; }
                else       { dst = src = t - E; }
                int bk = dst >> 6;
                int r = atomicAdd(&cur2[bk], 1);          // LDS cursor
                stg[r] = ((unsigned)dst << 16) | (unsigned)src;
            }
        }
        __syncthreads();
        // p5: coalesced run writeout
        for (int i = tid; i < tot; i += 256) {
            unsigned v = stg[i];
            int bk = v >> 22;                              // dst>>6
            int pos = cnt[bk] + (i - off[bk]);
            if (pos < BCAP)
                buck[(size_t)bk * BCAP + pos] = v;
        }
        return;
    }

    // ---- GEMM tile block (== R27) ----
    const int tid = threadIdx.x;
    const int lane = tid & 63;
    const int wid = tid >> 6;
    const int quad = lane >> 4;
    const int l16 = lane & 15;
    const int row = blockIdx.x * 64 + wid * 16 + l16;

    const float4* x4 = (const float4*)x;
    short8 afrag[4];
#pragma unroll
    for (int kt = 0; kt < 4; ++kt) {
        float4 f0 = make_float4(0.f, 0.f, 0.f, 0.f), f1 = f0;
        if (row < n) {
            f0 = x4[(size_t)row * 32 + kt * 8 + quad * 2];
            f1 = x4[(size_t)row * 32 + kt * 8 + quad * 2 + 1];
        }
        short8 a;
        a[0] = (short)bf16rne(f0.x); a[1] = (short)bf16rne(f0.y);
        a[2] = (short)bf16rne(f0.z); a[3] = (short)bf16rne(f0.w);
        a[4] = (short)bf16rne(f1.x); a[5] = (short)bf16rne(f1.y);
        a[6] = (short)bf16rne(f1.z); a[7] = (short)bf16rne(f1.w);
        afrag[kt] = a;
    }

    f32x4 acc[9];
#pragma unroll
    for (int ct = 0; ct < 9; ++ct) acc[ct] = (f32x4){0.f, 0.f, 0.f, 0.f};

#pragma unroll
    for (int ct = 0; ct < 9; ++ct) {
#pragma unroll
        for (int kt = 0; kt < 4; ++kt) {
            short8 bfr = *(const short8*)&Wtg[(size_t)(ct * 16 + l16) * 128 + kt * 32 + quad * 8];
            acc[ct] = __builtin_amdgcn_mfma_f32_16x16x32_bf16(afrag[kt], bfr, acc[ct], 0, 0, 0);
        }
    }

    const int rowbase = blockIdx.x * 64 + wid * 16 + quad * 4;
#pragma unroll
    for (int ct = 0; ct < 8; ++ct) {
#pragma unroll
        for (int r = 0; r < 4; ++r) {
            float val = acc[ct][r];
            float other = __shfl_xor(val, 1);
            int orow = rowbase + r;
            if (!(lane & 1) && orow < n) {
                unsigned u = bf16rne(val) | (bf16rne(other) << 16);
                xpb[(size_t)orow * 64 + ct * 8 + (l16 >> 1)] = u;
            }
        }
    }
#pragma unroll
    for (int r = 0; r < 4; ++r) {
        int orow = rowbase + r;
        if (orow < n) {
            float val = acc[8][r];
            if (l16 < 8) a_s[(size_t)orow * 8 + l16] = val;
            else         a_d[(size_t)orow * 8 + (l16 - 8)] = val;
        }
    }
}

// ---------------------------------------------------------------------------
// K2: per-bucket finish (== R27). LDS counting sort by dst&63 ->
// deg/rowst + coalesced writeback.
// ---------------------------------------------------------------------------
__global__ __launch_bounds__(256) void k_bfin(
    const int* __restrict__ bcur, unsigned* __restrict__ buck,
    int* __restrict__ deg, int* __restrict__ rowst, int n)
{
    const int k = blockIdx.x;
    const int start = k * BCAP;
    const int cnt = min(bcur[k], BCAP);
    __shared__ unsigned it[BCAP];
    __shared__ unsigned so[BCAP];
    __shared__ int h[64], pf[64], curs[64];
    for (int i = threadIdx.x; i < cnt; i += 256) it[i] = buck[start + i];
    if (threadIdx.x < 64) h[threadIdx.x] = 0;
    __syncthreads();
    for (int i = threadIdx.x; i < cnt; i += 256)
        atomicAdd(&h[(it[i] >> 16) & 63], 1);
    __syncthreads();
    if (threadIdx.x < 64) {
        int p = 0;
        for (int j = 0; j < threadIdx.x; ++j) p += h[j];
        pf[threadIdx.x] = p;
        curs[threadIdx.x] = p;
    }
    __syncthreads();
    for (int i = threadIdx.x; i < cnt; i += 256) {
        unsigned v = it[i];
        int r = atomicAdd(&curs[(v >> 16) & 63], 1);
        so[r] = v;
    }
    __syncthreads();
    for (int i = threadIdx.x; i < cnt; i += 256) buck[start + i] = so[i];
    if (threadIdx.x < 64) {
        int dst = (k << 6) + threadIdx.x;
        if (dst < n) {
            deg[dst] = h[threadIdx.x];
            rowst[dst] = start + pf[threadIdx.x];
        }
    }
}

// ---------------------------------------------------------------------------
// K3: per-dst gather-aggregate from the sorted bucket array. (== R27)
// ---------------------------------------------------------------------------
__global__ __launch_bounds__(256) void k_gather(
    const int* __restrict__ deg, const int* __restrict__ rowst,
    const unsigned* __restrict__ buck,
    const float* __restrict__ a_s, const float* __restrict__ a_d,
    const unsigned* __restrict__ xpb, unsigned* __restrict__ aggb, int n)
{
    int node = blockIdx.x * 4 + (threadIdx.x >> 6);
    if (node >= n) return;
    int lane = threadIdx.x & 63;
    int h = lane >> 3;
    float ad = a_d[(size_t)node * 8 + h];
    const unsigned* rowp = buck + rowst[node];
    int cnt = deg[node];
    float acc0 = 0.f, acc1 = 0.f, s = 0.f;

    for (int slot = 0; slot < cnt; slot += 8) {
        int sx[8]; float w[8]; unsigned u[8];
#pragma unroll
        for (int j = 0; j < 8; ++j) {
            int sj = slot + j;
            sx[j] = (int)(rowp[sj < cnt ? sj : cnt - 1] & 0xffffu);
        }
#pragma unroll
        for (int j = 0; j < 8; ++j) w[j] = a_s[(size_t)sx[j] * 8 + h];
#pragma unroll
        for (int j = 0; j < 8; ++j) u[j] = xpb[(size_t)sx[j] * 64 + lane];
#pragma unroll
        for (int j = 0; j < 8; ++j) {
            float v = w[j] + ad;
            v = v > 0.f ? v : NEG_SLOPE * v;
            float p = __expf(v);
            p = (slot + j < cnt) ? p : 0.f;
            s += p;
            acc0 = fmaf(p, __uint_as_float(u[j] << 16), acc0);
            acc1 = fmaf(p, __uint_as_float(u[j] & 0xffff0000u), acc1);
        }
    }
    float inv = 1.0f / (s + SM_EPS);
    aggb[(size_t)node * 64 + lane] = bf16rne(acc0 * inv) | (bf16rne(acc1 * inv) << 16);
}

// ---------------------------------------------------------------------------
// K4: per-channel sum / sumsq of agg (bf16). (== R27)
// ---------------------------------------------------------------------------
__global__ __launch_bounds__(256) void k_bnstats(
    const unsigned* __restrict__ aggb, int n, float* __restrict__ stats)
{
    __shared__ float red[4][256];   // [rowgroup][0:128 sums | 128:256 sumsq]
    const int cp = threadIdx.x & 63;       // channel pair: c = 2cp, 2cp+1
    const int rg = threadIdx.x >> 6;       // row group 0..3
    float s0 = 0.f, s1 = 0.f, q0 = 0.f, q1 = 0.f;
    for (int r = blockIdx.x * 4 + rg; r < n; r += gridDim.x * 4) {
        unsigned u = aggb[(size_t)r * 64 + cp];
        float v0 = __uint_as_float(u << 16);
        float v1 = __uint_as_float(u & 0xffff0000u);
        s0 += v0; q0 += v0 * v0;
        s1 += v1; q1 += v1 * v1;
    }
    red[rg][cp * 2] = s0;       red[rg][cp * 2 + 1] = s1;
    red[rg][128 + cp * 2] = q0; red[rg][128 + cp * 2 + 1] = q1;
    __syncthreads();
    int idx = threadIdx.x;
    float v = red[0][idx] + red[1][idx] + red[2][idx] + red[3][idx];
    if (idx < 128) atomicAdd(&stats[idx], v);
    else           atomicAdd(&stats[128 + (idx - 128)], v);
}

// ---------------------------------------------------------------------------
// K5: finalize: BN (batch stats of agg) + ReLU + residual. (== R27)
// ---------------------------------------------------------------------------
__global__ __launch_bounds__(256) void k_final(
    const unsigned* __restrict__ aggb, const float* __restrict__ gamma,
    const float* __restrict__ beta, const float* __restrict__ stats,
    const float* __restrict__ x, float* __restrict__ out, int n)
{
    int i4 = blockIdx.x * 256 + threadIdx.x;     // index in float4 units
    int total4 = n * 32;
    if (i4 >= total4) return;
    int c4 = (i4 & 31) * 4;                      // channel base
    float invn = 1.0f / (float)n;
    uint2 au = ((const uint2*)aggb)[i4];         // 4 bf16
    float av[4] = { __uint_as_float(au.x << 16), __uint_as_float(au.x & 0xffff0000u),
                    __uint_as_float(au.y << 16), __uint_as_float(au.y & 0xffff0000u) };
    float4 xv = ((const float4*)x)[i4];
    float4 o;
#pragma unroll
    for (int j = 0; j < 4; ++j) {
        int c = c4 + j;
        float mean = stats[c] * invn;
        float var = stats[128 + c] * invn - mean * mean;
        float v = (av[j] - mean) * rsqrtf(var + BN_EPS) * gamma[c] + beta[c];
        v = fmaxf(v, 0.f);
        (&o.x)[j] = v + (&xv.x)[j];
    }
    ((float4*)out)[i4] = o;
}

// ---------------------------------------------------------------------------
extern "C" void kernel_launch(void* const* d_in, const int* in_sizes, int n_in,
                              void* d_out, int out_size, void* d_ws, size_t ws_size,
                              hipStream_t stream)
{
    const float* x        = (const float*)d_in[0];
    const int*   ei       = (const int*)d_in[1];
    const float* W        = (const float*)d_in[2];
    const float* att_src  = (const float*)d_in[3];
    const float* att_dst  = (const float*)d_in[4];
    const float* bn_gamma = (const float*)d_in[6];
    const float* bn_beta  = (const float*)d_in[7];
    float* out = (float*)d_out;

    const int n = in_sizes[0] / 128;
    const int E = in_sizes[1] / 2;
    const int T = E + n;
    const int nba = (T + IPB - 1) / IPB;         // 84 scatter blocks

    // workspace layout: stats | bcur | deg contiguous (zeroed in init)
    float*          stats = (float*)d_ws;                         // 256
    int*            bcur  = (int*)(stats + 256);                  // NBUCK
    int*            deg   = bcur + NBUCK;                         // n
    int*            rowst = deg + n;                              // n
    unsigned short* Wtg   = (unsigned short*)(rowst + n);         // 144*128
    unsigned*       xpb   = (unsigned*)(Wtg + 144 * 128);         // n*64 (bf16 x2)
    unsigned*       aggb  = xpb + (size_t)n * 64;                 // n*64 (bf16 x2)
    float*          a_s   = (float*)(aggb + (size_t)n * 64);      // n*8
    float*          a_d   = a_s + (size_t)n * 8;                  // n*8
    unsigned*       buck  = (unsigned*)(a_d + (size_t)n * 8);     // NBUCK*BCAP

    const int zcount = 256 + NBUCK + n;
    const int ginit = 72 + (zcount + 255) / 256;
    const int ntiles = (n + 63) >> 6;
    const int ggemm = ntiles + nba;              // 625 + 84 = 709

    k_init<<<ginit, 256, 0, stream>>>(W, att_src, att_dst, Wtg,
                                      (int*)stats, zcount);
    k_gemm<<<ggemm, 256, 0, stream>>>(x, Wtg, ei, E, xpb, a_s, a_d,
                                      bcur, buck, n, ntiles);
    k_bfin<<<NBUCK, 256, 0, stream>>>(bcur, buck, deg, rowst, n);
    k_gather<<<(n + 3) / 4, 256, 0, stream>>>(deg, rowst, buck, a_s, a_d,
                                              xpb, aggb, n);
    k_bnstats<<<640, 256, 0, stream>>>(aggb, n, stats);
    k_final<<<(n * 32 + 255) / 256, 256, 0, stream>>>(aggb, bn_gamma, bn_beta,
                                                      stats, x, out, n);
}